// Round 4
// baseline (66.447 us; speedup 1.0000x reference)
//
#include <hip/hip_runtime.h>

// Problem constants (fixed by the reference setup)
#define Bc   2
#define Cc   256
#define Hc   80
#define Wc   160
#define Gc   4
#define Sc   9
#define GCc  64              // channels per group
#define HWc  (Hc * Wc)
#define H2c  (Hc / 2)        // 40 row-pair tiles
#define WTc  (Wc / 32)       // 5 col tiles of 32
#define NW   4               // waves per block
#define CPW  16              // channels per wave (4 waves split a group)

// LDS staging region (per wave, double-buffered)
#define RROWS   19
#define RCOLS   64
#define RSTRIDE 65           // +1 pad

typedef const __attribute__((address_space(1))) unsigned int* gas_ptr;
typedef __attribute__((address_space(3))) unsigned int* las_ptr;

// Block = 256 threads = 4 waves, all on the same (b, g, 2x32 pixel tile);
// wave w handles channels [w*16, w*16+16), 4-way LDS reduce at the end.
// Per wave: double-buffered LDS staging of the sample footprint with a
// COUNTED vmcnt (stage of channel c+1 in flight under channel c's compute).
// R3 was latency-bound at 12.5 waves/CU; RROWS 24->19 + 4 waves/block gives
// 39.5KB/block -> 4 blocks/CU -> 16 waves/CU.
__global__ __launch_bounds__(256, 4)
void aoc_corr_kernel(const float* __restrict__ left,
                     const float* __restrict__ right,
                     const float* __restrict__ flow,
                     const float* __restrict__ extra,
                     float* __restrict__ out)
{
    // [wave][buf][region]; reduce buffer aliased onto this after compute.
    __shared__ float tile[NW][2][RROWS * RSTRIDE];

    int bid = blockIdx.x;
    int wt = bid % WTc; bid /= WTc;
    int h2 = bid % H2c; bid /= H2c;
    int g  = bid % Gc;  bid /= Gc;
    int b  = bid;

    const int tid  = threadIdx.x;
    const int wid  = tid >> 6;
    const int lane = tid & 63;
    const int r    = lane >> 5;
    const int col  = lane & 31;
    const int h    = h2 * 2 + r;
    const int w    = wt * 32 + col;
    const int pix  = h * Wc + w;

    const float* flowb = flow + (size_t)b * 2 * HWc;
    const float bx = (float)w + flowb[pix];
    const float by = (float)h + flowb[HWc + pix];

    int   xb9[Sc], y09[Sc], y19[Sc];
    float w00[Sc], w01[Sc], w10[Sc], w11[Sc];
    int minX = 1 << 30, maxX = -(1 << 30), minY = 1 << 30, maxY = -(1 << 30);

    const float* exb = extra + (size_t)b * (2 * Sc) * HWc + pix;
#pragma unroll
    for (int s = 0; s < Sc; ++s) {
        const float ex = exb[(size_t)(2 * s) * HWc];
        const float ey = exb[(size_t)(2 * s + 1) * HWc];
        const float x = bx + (float)(s - 4) + ex;   // window: x offset s-4, y 0
        const float y = by + ey;

        const float x0f = floorf(x);
        const float y0f = floorf(y);
        const float fx = x - x0f;
        const float fy = y - y0f;
        const int x0 = (int)x0f;
        const int y0 = (int)y0f;
        const int y1 = y0 + 1;

        const int xb = min(max(x0, 0), Wc - 2);
        const float cA = (x0 == xb) ? (1.0f - fx) : ((x0 == -1)     ? fx          : 0.0f);
        const float cB = (x0 == xb) ? fx          : ((x0 == Wc - 1) ? (1.0f - fx) : 0.0f);
        const float r0 = (y0 >= 0 && y0 < Hc) ? (1.0f - fy) : 0.0f;
        const float r1 = (y1 >= 0 && y1 < Hc) ? fy          : 0.0f;
        const int yc0 = min(max(y0, 0), Hc - 1);
        const int yc1 = min(max(y1, 0), Hc - 1);

        w00[s] = cA * r0;  w01[s] = cB * r0;
        w10[s] = cA * r1;  w11[s] = cB * r1;
        xb9[s] = xb;  y09[s] = yc0;  y19[s] = yc1;

        minX = min(minX, xb);
        maxX = max(maxX, xb);
        minY = min(minY, min(yc0, yc1));
        maxY = max(maxY, max(yc0, yc1));
    }

    // Wave-wide min/max of the clamped footprint (identical across waves)
#pragma unroll
    for (int k = 1; k < 64; k <<= 1) {
        minX = min(minX, __shfl_xor(minX, k));
        maxX = max(maxX, __shfl_xor(maxX, k));
        minY = min(minY, __shfl_xor(minY, k));
        maxY = max(maxY, __shfl_xor(maxY, k));
    }
    const int nRows = maxY - minY + 1;
    const int nCols = maxX + 2 - minX;

    const float* Rb = right + ((size_t)b * Cc + (size_t)(g * GCc + wid * CPW)) * HWc;
    const float* Lb = left  + ((size_t)b * Cc + (size_t)(g * GCc + wid * CPW)) * HWc + pix;

    float acc[Sc];
#pragma unroll
    for (int s = 0; s < Sc; ++s) acc[s] = 0.0f;

    if (nRows <= RROWS && nCols <= RCOLS) {
        // One LDS base address per sample; the 4 corners are imm offsets
        // (0,1,65,66 dwords) -> 2x ds_read2_b32 per sample, zero per-iter VALU.
        const float* tl0 = tile[wid][0];
        const float* tl1 = tile[wid][1];
        int rel[Sc];
#pragma unroll
        for (int s = 0; s < Sc; ++s)
            rel[s] = (y09[s] - minY) * RSTRIDE + (xb9[s] - minX);
        // B-row (y1) may be above or below y0; express as rel + dRow*RSTRIDE
        // with dRow in {-?,..}: y1 = y0+1 pre-clamp, post-clamp y19-y09 is 0 or 1.
        int dB[Sc];
#pragma unroll
        for (int s = 0; s < Sc; ++s) dB[s] = (y19[s] - y09[s]) * RSTRIDE;

        // Hoisted stage addressing: row offsets are wave-uniform (SGPRs)
        const int colAbs = minX + min(lane, (Wc - 1) - minX);
        int rowOff[RROWS];
#pragma unroll
        for (int rr = 0; rr < RROWS; ++rr)
            rowOff[rr] = min(minY + rr, Hc - 1) * Wc;

        auto stage = [&](int bufi, int c) {
            const float* Rc = Rb + (size_t)c * HWc;
#pragma unroll
            for (int rr = 0; rr < RROWS; ++rr) {
                __builtin_amdgcn_global_load_lds(
                    (gas_ptr)(Rc + rowOff[rr] + colAbs),
                    (las_ptr)&tile[wid][bufi][rr * RSTRIDE], 4, 0, 0);
            }
        };

        stage(0, 0);
        float lv = Lb[0];
        for (int c = 0; c < CPW; ++c) {
            const int cur = c & 1;
            // WAR: previous iter's LDS reads retired before overwriting buf
            asm volatile("s_waitcnt lgkmcnt(0)" ::: "memory");
            float lvn = 0.0f;
            if (c + 1 < CPW) {
                stage(cur ^ 1, c + 1);
                // stage(c) complete; stage(c+1)'s RROWS loads stay in flight
                asm volatile("s_waitcnt vmcnt(19)" ::: "memory");
                lvn = Lb[(size_t)(c + 1) * HWc];
            } else {
                asm volatile("s_waitcnt vmcnt(0)" ::: "memory");
            }
            const float* tl = cur ? tl1 : tl0;
#pragma unroll
            for (int s = 0; s < Sc; ++s) {
                const float* p = tl + rel[s];
                const float vA0 = p[0];
                const float vA1 = p[1];
                const float vB0 = p[dB[s]];
                const float vB1 = p[dB[s] + 1];
                acc[s] += lv * (w00[s] * vA0 + w01[s] * vA1 +
                                w10[s] * vB0 + w11[s] * vB1);
            }
            lv = lvn;
        }
    } else {
        // Fallback: direct global gathers (proven path; footprint outliers)
        int offA[Sc], offB[Sc];
#pragma unroll
        for (int s = 0; s < Sc; ++s) {
            offA[s] = y09[s] * Wc + xb9[s];
            offB[s] = y19[s] * Wc + xb9[s];
        }
        for (int c = 0; c < CPW; ++c) {
            const float lv = Lb[(size_t)c * HWc];
            const float* Rc = Rb + (size_t)c * HWc;
#pragma unroll
            for (int s = 0; s < Sc; ++s) {
                const float vA0 = Rc[offA[s]];
                const float vA1 = Rc[offA[s] + 1];
                const float vB0 = Rc[offB[s]];
                const float vB1 = Rc[offB[s] + 1];
                acc[s] += lv * (w00[s] * vA0 + w01[s] * vA1 +
                                w10[s] * vB0 + w11[s] * vB1);
            }
        }
    }

    // 4-way cross-wave reduction; reduce buffer aliases the dead tile memory.
    float* red = &tile[0][0][0];   // (NW-1) * Sc * 64 floats = 6912 B
    __syncthreads();
    if (wid != 0) {
#pragma unroll
        for (int s = 0; s < Sc; ++s)
            red[((wid - 1) * Sc + s) * 64 + lane] = acc[s];
    }
    __syncthreads();
    if (wid == 0) {
        const float inv = 1.0f / (float)GCc;
        float* ob = out + ((size_t)b * Gc + g) * Sc * HWc + pix;
#pragma unroll
        for (int s = 0; s < Sc; ++s) {
            float v = acc[s];
#pragma unroll
            for (int ww = 1; ww < NW; ++ww)
                v += red[((ww - 1) * Sc + s) * 64 + lane];
            ob[(size_t)s * HWc] = v * inv;
        }
    }
}

extern "C" void kernel_launch(void* const* d_in, const int* in_sizes, int n_in,
                              void* d_out, int out_size, void* d_ws, size_t ws_size,
                              hipStream_t stream) {
    const float* left  = (const float*)d_in[0];
    const float* right = (const float*)d_in[1];
    const float* flow  = (const float*)d_in[2];
    const float* extra = (const float*)d_in[3];
    float* out = (float*)d_out;

    const int nblocks = Bc * Gc * H2c * WTc;  // 2*4*40*5 = 1600
    aoc_corr_kernel<<<nblocks, NW * 64, 0, stream>>>(left, right, flow, extra, out);
}